// Round 6
// baseline (26.084 us; speedup 1.0000x reference)
//
#include <hip/hip_runtime.h>

// out[i, j] = (j >= k_i) ? 1 : 0 with k_i = (int)(rint(x_i*8)/8 * 2048)
//           = rint(x_i*8) * 256  -> always a multiple of 256.
// jnp.round = round-half-to-even = rintf (default RNE rounding mode).
// Output 8192 x 4096 fp32 = 128 MiB -> pure HBM-write-bound.
//
// R6: fill-style launch. The runtime fillBufferAligned kernels sustain
// 6.7-6.9 TB/s at ~10% occupancy (small grid-stride); our max-occupancy
// launches (R2/R5) plateau at 5.5 TB/s. Test: 256 blocks x 256 threads,
// grid-stride, 128 float4 per thread. Store pattern unchanged (dwordx4,
// wave writes 1 KiB contiguous, no nt).

#define IN_CHANNEL 4096
#define BATCH 8192
#define ROW_F4 (IN_CHANNEL / 4)         // 1024 float4 per row
#define TOTAL_F4 (BATCH * ROW_F4)       // 8,388,608
#define NBLOCKS 256
#define NTHREADS 256

typedef float f32x4 __attribute__((ext_vector_type(4)));

__global__ void __launch_bounds__(NTHREADS) embprob_kernel(
    const float* __restrict__ x, f32x4* __restrict__ out) {
    const int stride = NBLOCKS * NTHREADS;          // 65536 float4 / iter
    int i = blockIdx.x * NTHREADS + threadIdx.x;
    #pragma unroll 4
    for (; i < TOTAL_F4; i += stride) {
        const int row = i >> 10;                    // / ROW_F4 (wave-uniform)
        const int col = (i & (ROW_F4 - 1)) << 2;    // element column
        const float xv = x[row];
        const int k = (int)rintf(xv * 8.0f) * 256;  // cutoff, multiple of 256
        const float v = (col >= k) ? 1.0f : 0.0f;
        f32x4 val = {v, v, v, v};
        out[i] = val;
    }
}

extern "C" void kernel_launch(void* const* d_in, const int* in_sizes, int n_in,
                              void* d_out, int out_size, void* d_ws, size_t ws_size,
                              hipStream_t stream) {
    const float* x = (const float*)d_in[0];
    f32x4* out = (f32x4*)d_out;
    embprob_kernel<<<NBLOCKS, NTHREADS, 0, stream>>>(x, out);
}

// Round 7
// 24.460 us; speedup vs baseline: 1.0664x; 1.0664x over previous
//
#include <hip/hip_runtime.h>

// out[i, j] = (j >= k_i) ? 1 : 0 with k_i = (int)(rint(x_i*8)/8 * 2048)
//           = rint(x_i*8) * 256  -> always a multiple of 256.
// jnp.round = round-half-to-even = rintf (default RNE rounding mode).
// Output 8192 x 4096 fp32 = 128 MiB -> pure HBM-write-bound (single pass
// is mandatory; no byte can be skipped).
//
// Config history: R2 8192x256 (1 row/blk)   = 24.6 us (5.45 TB/s)
//                 R5 2048x256 (4 rows/blk)  = 24.4 us (5.51 TB/s)
//                 R4 = R5 + nt stores       = 30.0 us (nt bypasses L2
//                     write-coalescing -> regression; never use for streams)
//                 R6 256x256 grid-stride    = 26.1 us (low occupancy hurts)
// R7: midpoint occupancy — 1024 blocks (4/CU), 32 f4/thread, unrolled.

#define IN_CHANNEL 4096
#define BATCH 8192
#define ROW_F4 (IN_CHANNEL / 4)         // 1024 float4 per row
#define TOTAL_F4 (BATCH * ROW_F4)       // 8,388,608
#define NBLOCKS 1024
#define NTHREADS 256

typedef float f32x4 __attribute__((ext_vector_type(4)));

__global__ void __launch_bounds__(NTHREADS) embprob_kernel(
    const float* __restrict__ x, f32x4* __restrict__ out) {
    // Each block owns a contiguous 8192-f4 chunk = 8 full rows.
    const int row0 = blockIdx.x * 8;
    const int t = threadIdx.x;
    #pragma unroll
    for (int r = 0; r < 8; ++r) {
        const int row = row0 + r;
        const float xv = x[row];                    // wave-uniform
        const int k = (int)rintf(xv * 8.0f) * 256;  // cutoff, multiple of 256
        f32x4* rowp = out + (size_t)row * ROW_F4;
        #pragma unroll
        for (int u = 0; u < 4; ++u) {
            const int f4 = t + u * 256;
            const int col = f4 << 2;
            const float v = (col >= k) ? 1.0f : 0.0f;
            f32x4 val = {v, v, v, v};
            rowp[f4] = val;
        }
    }
}

extern "C" void kernel_launch(void* const* d_in, const int* in_sizes, int n_in,
                              void* d_out, int out_size, void* d_ws, size_t ws_size,
                              hipStream_t stream) {
    const float* x = (const float*)d_in[0];
    f32x4* out = (f32x4*)d_out;
    embprob_kernel<<<NBLOCKS, NTHREADS, 0, stream>>>(x, out);
}